// Round 8
// baseline (2572.651 us; speedup 1.0000x reference)
//
#include <hip/hip_runtime.h>
#include <hip/hip_bf16.h>

// BiLSTM-CRF forward, MI355X gfx950.
// B=256, S=512, E=256, H=256, G=4H=1024, T=32, PAD=49999.
//
// Round-8 structure (single fused producer/consumer kernel):
//   K0 cvt_weights : W_ih -> bf16, W_hh/W_out -> fp8 e4m3; zero handshake flags
//   K1 fused       : 256 WGs x 512 thr, all co-resident (1 WG/CU).
//      WGs 0..31  (rec):  WG = (16-sentence group, dir). fp8 W_hh fully
//                         VGPR-resident; per step acc = gx + W_hh@h; gates f32;
//                         h via LDS fp8 parity buffers (1 barrier/step); fused
//                         fp8 emission (waves 0-1); h/c state in registers for
//                         all 512 steps. Waits once per 32-step chunk on gx_done.
//      WGs 32..255 (gemm): produce gx chunk tiles (128 gates x 64 sents x 8 s),
//                         embedding gathered in-kernel, into a 2-slot ring
//                         (33.5 MB/slot). Backpressure via rec_done counters.
//      Handshake: per-(chunk, bt) counters, agent-scope release-add +
//      relaxed spin + acquire fence — once per chunk, not per step.
//   K2 crf_kernel  : real-path score + CRF forward, 2-deep emit prefetch.

typedef __bf16 bf16x8 __attribute__((ext_vector_type(8)));
typedef float f32x4 __attribute__((ext_vector_type(4)));
typedef unsigned int uint4v __attribute__((ext_vector_type(4)));

#define SLOT_ELEMS 16777216ull   // 2 dirs x 32 s x 256 b x 1024 g (bf16 elems)

__device__ __forceinline__ unsigned short f2bf(float f) {
  union { float f; unsigned int u; } v; v.f = f;
  unsigned int r = v.u + 0x7fffu + ((v.u >> 16) & 1u);   // RNE
  return (unsigned short)(r >> 16);
}
__device__ __forceinline__ float bf2f(unsigned int lo16) {
  union { unsigned int u; float f; } v; v.u = lo16 << 16;
  return v.f;
}
__device__ __forceinline__ float fsig(float x) {
  float e = __builtin_amdgcn_exp2f(-1.4426950408889634f * x);
  return __builtin_amdgcn_rcpf(1.0f + e);
}
__device__ __forceinline__ float ftanh(float x) {
  float e = __builtin_amdgcn_exp2f(2.8853900817779268f * x);
  return 1.0f - 2.0f * __builtin_amdgcn_rcpf(e + 1.0f);
}

// ---------------- K0: weight conversion + flag zeroing ----------------
__global__ void cvt_weights(const float* __restrict__ wih_f, const float* __restrict__ wih_b,
                            const float* __restrict__ whh_f, const float* __restrict__ whh_b,
                            const float* __restrict__ wo,
                            unsigned short* __restrict__ wih,    // bf16 [2][1024][256]
                            unsigned char* __restrict__ whh8,    // fp8  [2][1024][256]
                            unsigned char* __restrict__ wout8,   // fp8  [32][512]
                            unsigned int* __restrict__ flg) {    // 128 u32
  if (blockIdx.x == 0 && threadIdx.x < 128) flg[threadIdx.x] = 0u;
  int t = blockIdx.x * 256 + threadIdx.x;
  int i = t * 4;
  if (i < 524288) {
    const float* src = (i < 262144) ? wih_f : wih_b;
    f32x4 v = *(const f32x4*)(src + (i & 262143));
    uint2 p;
    p.x = f2bf(v[0]) | ((unsigned int)f2bf(v[1]) << 16);
    p.y = f2bf(v[2]) | ((unsigned int)f2bf(v[3]) << 16);
    *(uint2*)(wih + i) = p;
  } else if (i < 1048576) {
    int k = i - 524288;
    const float* src = (k < 262144) ? whh_f : whh_b;
    f32x4 v = *(const f32x4*)(src + (k & 262143));
    int r = 0;
    r = __builtin_amdgcn_cvt_pk_fp8_f32(v[0], v[1], r, false);
    r = __builtin_amdgcn_cvt_pk_fp8_f32(v[2], v[3], r, true);
    *(unsigned int*)(whh8 + k) = (unsigned int)r;
  } else if (i < 1064960) {
    int k = i - 1048576;
    f32x4 v = *(const f32x4*)(wo + k);
    int r = 0;
    r = __builtin_amdgcn_cvt_pk_fp8_f32(v[0], v[1], r, false);
    r = __builtin_amdgcn_cvt_pk_fp8_f32(v[2], v[3], r, true);
    *(unsigned int*)(wout8 + k) = (unsigned int)r;
  }
}

// ---------------- K1: fused gemm-producer / lstm-consumer ----------------
__global__ __launch_bounds__(512, 2) void fused(
    const float* __restrict__ emb, const int* __restrict__ sent, const int* __restrict__ lens,
    const unsigned short* __restrict__ wih,    // bf16 [2][1024][256]
    const unsigned char* __restrict__ whh8,    // fp8  [2][1024][256]
    const unsigned char* __restrict__ wout8,   // fp8  [32][512]
    const float* __restrict__ bih_f, const float* __restrict__ bhh_f,
    const float* __restrict__ bih_b, const float* __restrict__ bhh_b,
    const float* __restrict__ bout,
    unsigned short* __restrict__ gx,           // 2 slots x SLOT_ELEMS bf16
    unsigned short* __restrict__ emit_f, unsigned short* __restrict__ emit_b,
    unsigned int* __restrict__ flg)            // gx_done[16][4], rec_done[16][4]
{
  __shared__ __align__(16) unsigned char SH[128 * 264 * 2 + 512];
  unsigned int* gxd = flg;        // [c][bt], target 64
  unsigned int* rcd = flg + 64;   // [c][bt], target 8
  int wg = blockIdx.x;
  int tid = threadIdx.x, w = tid >> 6, lane = tid & 63, col = lane & 15, q = lane >> 4;

  if (wg < 32) {
    // ================= rec path =================
    int dir = wg & 1, grp = wg >> 1, b0 = grp * 16, bt = grp >> 2;
    int maxlen = lens[b0];
    int mylen  = lens[b0 + col];
    unsigned char* hbuf = SH;   // [2][16*264] fp8

    // W_hh fp8 fragments fully resident (64 x 8B)
    const unsigned char* whb = whh8 + (size_t)dir * 262144;
    long wh[8][8];
#pragma unroll
    for (int kt = 0; kt < 8; kt++)
#pragma unroll
      for (int t = 0; t < 8; t++) {
        int row0 = (t & 3) * 256 + w * 32 + (t >> 2) * 16;
        wh[kt][t] = *(const long*)(whb + (size_t)(row0 + col) * 256 + kt * 32 + q * 8);
      }
    long wo8[8];
    f32x4 bo4 = (f32x4){0.f, 0.f, 0.f, 0.f};
    if (w < 2) {
#pragma unroll
      for (int kt = 0; kt < 8; kt++)
        wo8[kt] = *(const long*)(wout8 + (size_t)(w * 16 + col) * 512 + dir * 256 + kt * 32 + q * 8);
      if (dir == 0) {
#pragma unroll
        for (int r = 0; r < 4; r++) bo4[r] = bout[w * 16 + q * 4 + r];
      }
    }
    unsigned short* ebase = dir ? emit_b : emit_f;

    long hf8[8];
#pragma unroll
    for (int i = 0; i < 8; i++) hf8[i] = 0;
    float c8[8];
#pragma unroll
    for (int i = 0; i < 8; i++) c8[i] = 0.f;

    for (int c = 0; c < 16; c++) {
      int s0 = c * 32;
      if (s0 < maxlen) {
        if (tid == 0) {
          int guard = 0;
          while (__hip_atomic_load(&gxd[c * 4 + bt], __ATOMIC_RELAXED,
                                   __HIP_MEMORY_SCOPE_AGENT) < 64u) {
            if (++guard > 200000000) break;
          }
        }
        __syncthreads();
        __builtin_amdgcn_fence(__ATOMIC_ACQUIRE, "agent");

        int send = s0 + 32; if (send > maxlen) send = maxlen;
        const unsigned short* gl = gx + (size_t)(c & 1) * SLOT_ELEMS
                                   + ((size_t)dir * 32 * 256 + (b0 + col)) * 1024 + q * 4;
        uint2 gxr[8];
#pragma unroll
        for (int t = 0; t < 8; t++) {
          int row0 = (t & 3) * 256 + w * 32 + (t >> 2) * 16;
          gxr[t] = *(const uint2*)(gl + row0);
        }
        for (int s = s0; s < send; s++) {
          f32x4 acc[8];
#pragma unroll
          for (int t = 0; t < 8; t++) {
            f32x4 a;
            a[0] = bf2f(gxr[t].x & 0xffffu); a[1] = bf2f(gxr[t].x >> 16);
            a[2] = bf2f(gxr[t].y & 0xffffu); a[3] = bf2f(gxr[t].y >> 16);
            acc[t] = a;
          }
          {
            int snl = (s + 1 < send) ? (s + 1 - s0) : (send - 1 - s0);
            const unsigned short* gn = gl + (size_t)snl * 262144;
#pragma unroll
            for (int t = 0; t < 8; t++) {
              int row0 = (t & 3) * 256 + w * 32 + (t >> 2) * 16;
              gxr[t] = *(const uint2*)(gn + row0);
            }
          }
#pragma unroll
          for (int kt = 0; kt < 8; kt++) {
            long hv8 = hf8[kt];
#pragma unroll
            for (int t = 0; t < 8; t++)
              acc[t] = __builtin_amdgcn_mfma_f32_16x16x32_fp8_fp8(wh[kt][t], hv8, acc[t], 0, 0, 0);
          }
          float hv[8];
#pragma unroll
          for (int a = 0; a < 2; a++)
#pragma unroll
            for (int r = 0; r < 4; r++) {
              float ig = acc[a * 4 + 0][r], fg = acc[a * 4 + 1][r];
              float gg = acc[a * 4 + 2][r], og = acc[a * 4 + 3][r];
              float cn = fsig(fg) * c8[a * 4 + r] + fsig(ig) * ftanh(gg);
              c8[a * 4 + r] = cn;
              hv[a * 4 + r] = fsig(og) * ftanh(cn);
            }
          int par = s & 1;
#pragma unroll
          for (int a = 0; a < 2; a++) {
            int r8 = 0;
            r8 = __builtin_amdgcn_cvt_pk_fp8_f32(hv[a * 4 + 0], hv[a * 4 + 1], r8, false);
            r8 = __builtin_amdgcn_cvt_pk_fp8_f32(hv[a * 4 + 2], hv[a * 4 + 3], r8, true);
            *(unsigned int*)(&hbuf[par * 4224 + col * 264 + w * 32 + a * 16 + q * 4]) = (unsigned int)r8;
          }
          __syncthreads();
#pragma unroll
          for (int kt = 0; kt < 8; kt++)
            hf8[kt] = *(const long*)(&hbuf[par * 4224 + col * 264 + kt * 32 + q * 8]);

          if (w < 2) {
            f32x4 ea = bo4;
#pragma unroll
            for (int kt = 0; kt < 8; kt++)
              ea = __builtin_amdgcn_mfma_f32_16x16x32_fp8_fp8(wo8[kt], hf8[kt], ea, 0, 0, 0);
            if (s < mylen) {
              int pos = dir ? (mylen - 1 - s) : s;
              uint2 pk;
              pk.x = f2bf(ea[0]) | ((unsigned int)f2bf(ea[1]) << 16);
              pk.y = f2bf(ea[2]) | ((unsigned int)f2bf(ea[3]) << 16);
              *(uint2*)(ebase + (((size_t)(b0 + col) * 512 + pos) * 32 + w * 16 + q * 4)) = pk;
            }
          }
        }
        __syncthreads();   // all waves done reading this gx slot
      }
      if (tid == 0)
        __hip_atomic_fetch_add(&rcd[c * 4 + bt], 1u, __ATOMIC_RELAXED, __HIP_MEMORY_SCOPE_AGENT);
    }
  } else {
    // ================= gemm path =================
    int gid = wg - 32;
    unsigned short* wtile = (unsigned short*)SH;             // 128 x 264
    float* btile = (float*)(SH + 128 * 264 * 2);             // 128 f32
    int ns = w >> 2, cg = w & 3;

    for (int j = gid; j < 4096; j += 224) {
      int c = j >> 8, t = j & 255;
      int btq = t & 3, nc = (t >> 2) & 7, ss = (t >> 5) & 3, dir = (t >> 7) & 1;
      int sbase = c * 32 + ss * 8, n0 = nc * 128, bbase = btq * 64;
      if (c >= 2 && tid == 0) {
        int guard = 0;
        while (__hip_atomic_load(&rcd[(c - 2) * 4 + btq], __ATOMIC_RELAXED,
                                 __HIP_MEMORY_SCOPE_AGENT) < 8u) {
          if (++guard > 200000000) break;
        }
      }
      __syncthreads();   // backpressure + LDS reuse

      if (sbase < lens[bbase]) {
        const unsigned short* wsrc = wih + (size_t)dir * 262144;
#pragma unroll
        for (int it = 0; it < 8; it++) {
          int seg = it * 512 + tid;
          int row = seg >> 5, kc = (seg & 31) * 8;
          *(uint4v*)(wtile + row * 264 + kc) = *(const uint4v*)(wsrc + (size_t)(n0 + row) * 256 + kc);
        }
        const float* bi = dir ? bih_b : bih_f;
        const float* bh = dir ? bhh_b : bhh_f;
        if (tid < 128) btile[tid] = bi[n0 + tid] + bh[n0 + tid];
        __syncthreads();

        bf16x8 wf[8][4];
#pragma unroll
        for (int kt = 0; kt < 8; kt++)
#pragma unroll
          for (int nt = 0; nt < 4; nt++)
            wf[kt][nt] = *(const bf16x8*)(wtile + (ns * 64 + nt * 16 + col) * 264 + kt * 32 + q * 8);
        f32x4 bias[4];
#pragma unroll
        for (int nt = 0; nt < 4; nt++)
#pragma unroll
          for (int r = 0; r < 4; r++)
            bias[nt][r] = btile[ns * 64 + nt * 16 + q * 4 + r];

        int bidx = bbase + cg * 16 + col;
        int len = lens[bidx];
        const int* srow = sent + bidx * 512;
        unsigned short* gdst = gx + (size_t)(c & 1) * SLOT_ELEMS;

        for (int i = 0; i < 8; i++) {
          int s = sbase + i;
          int s_eff = dir ? ((s < len) ? (len - 1 - s) : s) : s;
          int token = srow[s_eff];
          const float* ep = emb + (size_t)token * 256;
          bf16x8 xf[8];
#pragma unroll
          for (int kt = 0; kt < 8; kt++) {
            f32x4 a0 = *(const f32x4*)(ep + kt * 32 + q * 8);
            f32x4 a1 = *(const f32x4*)(ep + kt * 32 + q * 8 + 4);
            uint4v pk;
            pk[0] = f2bf(a0[0]) | ((unsigned int)f2bf(a0[1]) << 16);
            pk[1] = f2bf(a0[2]) | ((unsigned int)f2bf(a0[3]) << 16);
            pk[2] = f2bf(a1[0]) | ((unsigned int)f2bf(a1[1]) << 16);
            pk[3] = f2bf(a1[2]) | ((unsigned int)f2bf(a1[3]) << 16);
            xf[kt] = __builtin_bit_cast(bf16x8, pk);
          }
          f32x4 acc[4];
#pragma unroll
          for (int nt = 0; nt < 4; nt++) acc[nt] = bias[nt];
#pragma unroll
          for (int kt = 0; kt < 8; kt++)
#pragma unroll
            for (int nt = 0; nt < 4; nt++)
              acc[nt] = __builtin_amdgcn_mfma_f32_16x16x32_bf16(wf[kt][nt], xf[kt], acc[nt], 0, 0, 0);
          size_t off = (((size_t)dir * 32 + (s - c * 32)) * 256 + bidx) * 1024 + n0 + ns * 64;
#pragma unroll
          for (int nt = 0; nt < 4; nt++) {
            uint2 pk;
            pk.x = f2bf(acc[nt][0]) | ((unsigned int)f2bf(acc[nt][1]) << 16);
            pk.y = f2bf(acc[nt][2]) | ((unsigned int)f2bf(acc[nt][3]) << 16);
            *(uint2*)(gdst + off + nt * 16 + q * 4) = pk;
          }
        }
      }
      __builtin_amdgcn_fence(__ATOMIC_RELEASE, "agent");
      __syncthreads();
      if (tid == 0)
        __hip_atomic_fetch_add(&gxd[c * 4 + btq], 1u, __ATOMIC_RELEASE, __HIP_MEMORY_SCOPE_AGENT);
    }
  }
}

// ---------------- K2: real-path score + CRF forward (prefetched) ----------------
__global__ void crf_kernel(const unsigned short* __restrict__ emit_f,
                           const unsigned short* __restrict__ emit_b,
                           const float* __restrict__ trans, const int* __restrict__ tags,
                           const int* __restrict__ lens, float* __restrict__ out) {
  const float LOG2E = 1.4426950408889634f, LN2 = 0.6931471805599453f;
  int b = blockIdx.x, lane = threadIdx.x;
  int len = lens[b];
  const int* tg = tags + b * 512;

  float rs = 0.f;
  for (int s = lane; s < len; s += 64) {
    int t1 = tg[s];
    size_t idx = ((size_t)b * 512 + s) * 32 + t1;
    float e = bf2f(emit_f[idx]) + bf2f(emit_b[idx]);
    if (s > 0) e += trans[tg[s - 1] * 32 + t1];
    rs += e;
  }
#pragma unroll
  for (int m = 32; m; m >>= 1) rs += __shfl_xor(rs, m);

  int j = lane & 31, half = lane >> 5, i0 = half * 16;
  float tr[16];
#pragma unroll
  for (int ii = 0; ii < 16; ii++) tr[ii] = trans[(i0 + ii) * 32 + j];
  size_t base = (size_t)b * 512 * 32 + j;
  float alpha = bf2f(emit_f[base]) + bf2f(emit_b[base]);
  float e1 = 0.f, e2 = 0.f;
  if (len > 1) e1 = bf2f(emit_f[base + 32]) + bf2f(emit_b[base + 32]);
  if (len > 2) e2 = bf2f(emit_f[base + 64]) + bf2f(emit_b[base + 64]);
  for (int s = 1; s < len; s++) {
    float e3 = 0.f;
    if (s + 2 < len) {
      size_t ix = base + (size_t)(s + 2) * 32;
      e3 = bf2f(emit_f[ix]) + bf2f(emit_b[ix]);
    }
    float v[16]; float m1 = -1e30f;
#pragma unroll
    for (int ii = 0; ii < 16; ii++) { v[ii] = __shfl(alpha, i0 + ii) + tr[ii]; m1 = fmaxf(m1, v[ii]); }
    float m2 = fmaxf(m1, __shfl_xor(m1, 32));
    float sum = 0.f;
#pragma unroll
    for (int ii = 0; ii < 16; ii++) sum += __builtin_amdgcn_exp2f((v[ii] - m2) * LOG2E);
    sum += __shfl_xor(sum, 32);
    alpha = m2 + LN2 * __builtin_amdgcn_logf(sum) + e1;   // amdgcn logf == log2
    e1 = e2; e2 = e3;
  }
  float mz = alpha;
#pragma unroll
  for (int m = 16; m; m >>= 1) mz = fmaxf(mz, __shfl_xor(mz, m));
  float sz = __builtin_amdgcn_exp2f((alpha - mz) * LOG2E);
#pragma unroll
  for (int m = 16; m; m >>= 1) sz += __shfl_xor(sz, m);
  float logz = mz + LN2 * __builtin_amdgcn_logf(sz);
  if (lane == 0) out[b] = logz - rs;
}

// ---------------- launch ----------------
extern "C" void kernel_launch(void* const* d_in, const int* in_sizes, int n_in,
                              void* d_out, int out_size, void* d_ws, size_t ws_size,
                              hipStream_t stream) {
  const float* emb   = (const float*)d_in[0];
  const float* Wih_f = (const float*)d_in[1];
  const float* Whh_f = (const float*)d_in[2];
  const float* bih_f = (const float*)d_in[3];
  const float* bhh_f = (const float*)d_in[4];
  const float* Wih_b = (const float*)d_in[5];
  const float* Whh_b = (const float*)d_in[6];
  const float* bih_b = (const float*)d_in[7];
  const float* bhh_b = (const float*)d_in[8];
  const float* Wout  = (const float*)d_in[9];
  const float* bout  = (const float*)d_in[10];
  const float* trans = (const float*)d_in[11];
  const int* sent = (const int*)d_in[12];
  const int* tags = (const int*)d_in[13];
  const int* lens = (const int*)d_in[14];
  float* out = (float*)d_out;

  // workspace layout (bytes), total 85,475,840
  char* ws = (char*)d_ws;
  if (ws_size < 85475840ull) return;
  unsigned short* gx      = (unsigned short*)(ws);                // 67,108,864 (2 slots)
  unsigned short* emit_f  = (unsigned short*)(ws + 67108864);     //  8,388,608
  unsigned short* emit_b  = (unsigned short*)(ws + 75497472);     //  8,388,608
  unsigned short* wih_bf  = (unsigned short*)(ws + 83886080);     //  1,048,576
  unsigned char*  whh8    = (unsigned char*)(ws + 84934656);      //    524,288
  unsigned char*  wout8   = (unsigned char*)(ws + 85458944);      //     16,384
  unsigned int*   flg     = (unsigned int*)(ws + 85475328);       //        512

  cvt_weights<<<1040, 256, 0, stream>>>(Wih_f, Wih_b, Whh_f, Whh_b, Wout,
                                        wih_bf, whh8, wout8, flg);
  fused<<<256, 512, 0, stream>>>(emb, sent, lens, wih_bf, whh8, wout8,
                                 bih_f, bhh_f, bih_b, bhh_b, bout,
                                 gx, emit_f, emit_b, flg);
  crf_kernel<<<256, 64, 0, stream>>>(emit_f, emit_b, trans, tags, lens, out);
}

// Round 9
// 2208.407 us; speedup vs baseline: 1.1649x; 1.1649x over previous
//
#include <hip/hip_runtime.h>
#include <hip/hip_bf16.h>

// BiLSTM-CRF forward, MI355X gfx950.
// B=256, S=512, E=256, H=256, G=4H=1024, T=32, PAD=49999.
//
// Round-9 structure (= round 8, but gx stored in rec-consumption PACKED layout):
//   gx packed: P[dir][s_loc 32][grp 16][w 8][t 8][lane 64] uint2 (8 B each);
//   producer (gemm) D-frag lane order == consumer (rec) lane order, so both
//   sides access 512 B contiguous per instruction (was a 16-segment gather).
//   K0 cvt_weights : W_ih -> bf16, W_hh/W_out -> fp8 e4m3; zero handshake flags
//   K1 fused       : 256 WGs x 512 thr. WGs 0..31 rec (fp8 W_hh VGPR/AGPR-resident,
//                    LDS h exchange, fused fp8 emission, in-register state, waits
//                    once per 32-step chunk); WGs 32..255 gemm producers into a
//                    2-slot ring with chunk-level release/acquire handshake.
//   K2 crf_kernel  : real-path score + CRF forward, 2-deep emit prefetch.

typedef __bf16 bf16x8 __attribute__((ext_vector_type(8)));
typedef float f32x4 __attribute__((ext_vector_type(4)));
typedef unsigned int uint4v __attribute__((ext_vector_type(4)));

#define SLOT_U2 4194304ull   // uint2 elems per slot: 2 dirs x 32 s x 16 grp x 8 w x 8 t x 64 lanes

__device__ __forceinline__ unsigned short f2bf(float f) {
  union { float f; unsigned int u; } v; v.f = f;
  unsigned int r = v.u + 0x7fffu + ((v.u >> 16) & 1u);   // RNE
  return (unsigned short)(r >> 16);
}
__device__ __forceinline__ float bf2f(unsigned int lo16) {
  union { unsigned int u; float f; } v; v.u = lo16 << 16;
  return v.f;
}
__device__ __forceinline__ float fsig(float x) {
  float e = __builtin_amdgcn_exp2f(-1.4426950408889634f * x);
  return __builtin_amdgcn_rcpf(1.0f + e);
}
__device__ __forceinline__ float ftanh(float x) {
  float e = __builtin_amdgcn_exp2f(2.8853900817779268f * x);
  return 1.0f - 2.0f * __builtin_amdgcn_rcpf(e + 1.0f);
}

// ---------------- K0: weight conversion + flag zeroing ----------------
__global__ void cvt_weights(const float* __restrict__ wih_f, const float* __restrict__ wih_b,
                            const float* __restrict__ whh_f, const float* __restrict__ whh_b,
                            const float* __restrict__ wo,
                            unsigned short* __restrict__ wih,    // bf16 [2][1024][256]
                            unsigned char* __restrict__ whh8,    // fp8  [2][1024][256]
                            unsigned char* __restrict__ wout8,   // fp8  [32][512]
                            unsigned int* __restrict__ flg) {    // 128 u32
  if (blockIdx.x == 0 && threadIdx.x < 128) flg[threadIdx.x] = 0u;
  int t = blockIdx.x * 256 + threadIdx.x;
  int i = t * 4;
  if (i < 524288) {
    const float* src = (i < 262144) ? wih_f : wih_b;
    f32x4 v = *(const f32x4*)(src + (i & 262143));
    uint2 p;
    p.x = f2bf(v[0]) | ((unsigned int)f2bf(v[1]) << 16);
    p.y = f2bf(v[2]) | ((unsigned int)f2bf(v[3]) << 16);
    *(uint2*)(wih + i) = p;
  } else if (i < 1048576) {
    int k = i - 524288;
    const float* src = (k < 262144) ? whh_f : whh_b;
    f32x4 v = *(const f32x4*)(src + (k & 262143));
    int r = 0;
    r = __builtin_amdgcn_cvt_pk_fp8_f32(v[0], v[1], r, false);
    r = __builtin_amdgcn_cvt_pk_fp8_f32(v[2], v[3], r, true);
    *(unsigned int*)(whh8 + k) = (unsigned int)r;
  } else if (i < 1064960) {
    int k = i - 1048576;
    f32x4 v = *(const f32x4*)(wo + k);
    int r = 0;
    r = __builtin_amdgcn_cvt_pk_fp8_f32(v[0], v[1], r, false);
    r = __builtin_amdgcn_cvt_pk_fp8_f32(v[2], v[3], r, true);
    *(unsigned int*)(wout8 + k) = (unsigned int)r;
  }
}

// ---------------- K1: fused gemm-producer / lstm-consumer ----------------
__global__ __launch_bounds__(512, 2) void fused(
    const float* __restrict__ emb, const int* __restrict__ sent, const int* __restrict__ lens,
    const unsigned short* __restrict__ wih,    // bf16 [2][1024][256]
    const unsigned char* __restrict__ whh8,    // fp8  [2][1024][256]
    const unsigned char* __restrict__ wout8,   // fp8  [32][512]
    const float* __restrict__ bih_f, const float* __restrict__ bhh_f,
    const float* __restrict__ bih_b, const float* __restrict__ bhh_b,
    const float* __restrict__ bout,
    uint2* __restrict__ gx,                    // 2 slots x SLOT_U2 uint2 (packed)
    unsigned short* __restrict__ emit_f, unsigned short* __restrict__ emit_b,
    unsigned int* __restrict__ flg)            // gx_done[16][4], rec_done[16][4]
{
  __shared__ __align__(16) unsigned char SH[128 * 264 * 2 + 512];
  unsigned int* gxd = flg;        // [c][bt], target 64
  unsigned int* rcd = flg + 64;   // [c][bt], target 8
  int wg = blockIdx.x;
  int tid = threadIdx.x, w = tid >> 6, lane = tid & 63, col = lane & 15, q = lane >> 4;

  if (wg < 32) {
    // ================= rec path =================
    int dir = wg & 1, grp = wg >> 1, b0 = grp * 16, bt = grp >> 2;
    int maxlen = lens[b0];
    int mylen  = lens[b0 + col];
    unsigned char* hbuf = SH;   // [2][16*264] fp8

    // W_hh fp8 fragments fully resident (64 x 8B)
    const unsigned char* whb = whh8 + (size_t)dir * 262144;
    long wh[8][8];
#pragma unroll
    for (int kt = 0; kt < 8; kt++)
#pragma unroll
      for (int t = 0; t < 8; t++) {
        int row0 = (t & 3) * 256 + w * 32 + (t >> 2) * 16;
        wh[kt][t] = *(const long*)(whb + (size_t)(row0 + col) * 256 + kt * 32 + q * 8);
      }
    long wo8[8];
    f32x4 bo4 = (f32x4){0.f, 0.f, 0.f, 0.f};
    if (w < 2) {
#pragma unroll
      for (int kt = 0; kt < 8; kt++)
        wo8[kt] = *(const long*)(wout8 + (size_t)(w * 16 + col) * 512 + dir * 256 + kt * 32 + q * 8);
      if (dir == 0) {
#pragma unroll
        for (int r = 0; r < 4; r++) bo4[r] = bout[w * 16 + q * 4 + r];
      }
    }
    unsigned short* ebase = dir ? emit_b : emit_f;

    long hf8[8];
#pragma unroll
    for (int i = 0; i < 8; i++) hf8[i] = 0;
    float c8[8];
#pragma unroll
    for (int i = 0; i < 8; i++) c8[i] = 0.f;

    for (int c = 0; c < 16; c++) {
      int s0 = c * 32;
      if (s0 < maxlen) {
        if (tid == 0) {
          int guard = 0;
          while (__hip_atomic_load(&gxd[c * 4 + bt], __ATOMIC_RELAXED,
                                   __HIP_MEMORY_SCOPE_AGENT) < 64u) {
            if (++guard > 200000000) break;
          }
        }
        __syncthreads();
        __builtin_amdgcn_fence(__ATOMIC_ACQUIRE, "agent");

        int send = s0 + 32; if (send > maxlen) send = maxlen;
        // packed: gl[t*64], per-s_loc stride 65536 uint2
        const uint2* gl = gx + (size_t)(c & 1) * SLOT_U2
                          + ((((size_t)dir * 32) * 16 + grp) * 8 + w) * 8 * 64 + lane;
        uint2 gxr[8];
#pragma unroll
        for (int t = 0; t < 8; t++) gxr[t] = gl[t * 64];
        for (int s = s0; s < send; s++) {
          f32x4 acc[8];
#pragma unroll
          for (int t = 0; t < 8; t++) {
            f32x4 a;
            a[0] = bf2f(gxr[t].x & 0xffffu); a[1] = bf2f(gxr[t].x >> 16);
            a[2] = bf2f(gxr[t].y & 0xffffu); a[3] = bf2f(gxr[t].y >> 16);
            acc[t] = a;
          }
          {
            int snl = (s + 1 < send) ? (s + 1 - s0) : (send - 1 - s0);
            const uint2* gn = gl + (size_t)snl * 65536;
#pragma unroll
            for (int t = 0; t < 8; t++) gxr[t] = gn[t * 64];
          }
#pragma unroll
          for (int kt = 0; kt < 8; kt++) {
            long hv8 = hf8[kt];
#pragma unroll
            for (int t = 0; t < 8; t++)
              acc[t] = __builtin_amdgcn_mfma_f32_16x16x32_fp8_fp8(wh[kt][t], hv8, acc[t], 0, 0, 0);
          }
          float hv[8];
#pragma unroll
          for (int a = 0; a < 2; a++)
#pragma unroll
            for (int r = 0; r < 4; r++) {
              float ig = acc[a * 4 + 0][r], fg = acc[a * 4 + 1][r];
              float gg = acc[a * 4 + 2][r], og = acc[a * 4 + 3][r];
              float cn = fsig(fg) * c8[a * 4 + r] + fsig(ig) * ftanh(gg);
              c8[a * 4 + r] = cn;
              hv[a * 4 + r] = fsig(og) * ftanh(cn);
            }
          int par = s & 1;
#pragma unroll
          for (int a = 0; a < 2; a++) {
            int r8 = 0;
            r8 = __builtin_amdgcn_cvt_pk_fp8_f32(hv[a * 4 + 0], hv[a * 4 + 1], r8, false);
            r8 = __builtin_amdgcn_cvt_pk_fp8_f32(hv[a * 4 + 2], hv[a * 4 + 3], r8, true);
            *(unsigned int*)(&hbuf[par * 4224 + col * 264 + w * 32 + a * 16 + q * 4]) = (unsigned int)r8;
          }
          __syncthreads();
#pragma unroll
          for (int kt = 0; kt < 8; kt++)
            hf8[kt] = *(const long*)(&hbuf[par * 4224 + col * 264 + kt * 32 + q * 8]);

          if (w < 2) {
            f32x4 ea = bo4;
#pragma unroll
            for (int kt = 0; kt < 8; kt++)
              ea = __builtin_amdgcn_mfma_f32_16x16x32_fp8_fp8(wo8[kt], hf8[kt], ea, 0, 0, 0);
            if (s < mylen) {
              int pos = dir ? (mylen - 1 - s) : s;
              uint2 pk;
              pk.x = f2bf(ea[0]) | ((unsigned int)f2bf(ea[1]) << 16);
              pk.y = f2bf(ea[2]) | ((unsigned int)f2bf(ea[3]) << 16);
              *(uint2*)(ebase + (((size_t)(b0 + col) * 512 + pos) * 32 + w * 16 + q * 4)) = pk;
            }
          }
        }
        __syncthreads();   // all waves done reading this gx slot
      }
      if (tid == 0)
        __hip_atomic_fetch_add(&rcd[c * 4 + bt], 1u, __ATOMIC_RELAXED, __HIP_MEMORY_SCOPE_AGENT);
    }
  } else {
    // ================= gemm path =================
    int gid = wg - 32;
    unsigned short* wtile = (unsigned short*)SH;             // 128 x 264
    float* btile = (float*)(SH + 128 * 264 * 2);             // 128 f32
    int ns = w >> 2, cg = w & 3;

    for (int j = gid; j < 4096; j += 224) {
      int c = j >> 8, t = j & 255;
      int btq = t & 3, nc = (t >> 2) & 7, ss = (t >> 5) & 3, dir = (t >> 7) & 1;
      int sbase = c * 32 + ss * 8, n0 = nc * 128, bbase = btq * 64;
      if (c >= 2 && tid == 0) {
        int guard = 0;
        while (__hip_atomic_load(&rcd[(c - 2) * 4 + btq], __ATOMIC_RELAXED,
                                 __HIP_MEMORY_SCOPE_AGENT) < 8u) {
          if (++guard > 200000000) break;
        }
      }
      __syncthreads();   // backpressure + LDS reuse

      if (sbase < lens[bbase]) {
        const unsigned short* wsrc = wih + (size_t)dir * 262144;
#pragma unroll
        for (int it = 0; it < 8; it++) {
          int seg = it * 512 + tid;
          int row = seg >> 5, kc = (seg & 31) * 8;
          *(uint4v*)(wtile + row * 264 + kc) = *(const uint4v*)(wsrc + (size_t)(n0 + row) * 256 + kc);
        }
        const float* bi = dir ? bih_b : bih_f;
        const float* bh = dir ? bhh_b : bhh_f;
        if (tid < 128) btile[tid] = bi[n0 + tid] + bh[n0 + tid];
        __syncthreads();

        bf16x8 wf[8][4];
#pragma unroll
        for (int kt = 0; kt < 8; kt++)
#pragma unroll
          for (int nt = 0; nt < 4; nt++)
            wf[kt][nt] = *(const bf16x8*)(wtile + (ns * 64 + nt * 16 + col) * 264 + kt * 32 + q * 8);
        f32x4 bias[4];
#pragma unroll
        for (int nt = 0; nt < 4; nt++)
#pragma unroll
          for (int r = 0; r < 4; r++)
            bias[nt][r] = btile[ns * 64 + nt * 16 + q * 4 + r];

        int grp = btq * 4 + cg;
        int bidx = grp * 16 + col;
        int len = lens[bidx];
        const int* srow = sent + bidx * 512;
        uint2* gdst = gx + (size_t)(c & 1) * SLOT_U2;

        for (int i = 0; i < 8; i++) {
          int s = sbase + i;
          int s_eff = dir ? ((s < len) ? (len - 1 - s) : s) : s;
          int token = srow[s_eff];
          const float* ep = emb + (size_t)token * 256;
          bf16x8 xf[8];
#pragma unroll
          for (int kt = 0; kt < 8; kt++) {
            f32x4 a0 = *(const f32x4*)(ep + kt * 32 + q * 8);
            f32x4 a1 = *(const f32x4*)(ep + kt * 32 + q * 8 + 4);
            uint4v pk;
            pk[0] = f2bf(a0[0]) | ((unsigned int)f2bf(a0[1]) << 16);
            pk[1] = f2bf(a0[2]) | ((unsigned int)f2bf(a0[3]) << 16);
            pk[2] = f2bf(a1[0]) | ((unsigned int)f2bf(a1[1]) << 16);
            pk[3] = f2bf(a1[2]) | ((unsigned int)f2bf(a1[3]) << 16);
            xf[kt] = __builtin_bit_cast(bf16x8, pk);
          }
          f32x4 acc[4];
#pragma unroll
          for (int nt = 0; nt < 4; nt++) acc[nt] = bias[nt];
#pragma unroll
          for (int kt = 0; kt < 8; kt++)
#pragma unroll
            for (int nt = 0; nt < 4; nt++)
              acc[nt] = __builtin_amdgcn_mfma_f32_16x16x32_bf16(wf[kt][nt], xf[kt], acc[nt], 0, 0, 0);
          int s_loc = s - c * 32;
#pragma unroll
          for (int nt = 0; nt < 4; nt++) {
            int gb = n0 + ns * 64 + nt * 16;
            int w_rec = (gb >> 5) & 7;
            int t_rec = ((gb >> 8) & 3) + (((gb >> 4) & 1) << 2);
            uint2 pk;
            pk.x = f2bf(acc[nt][0]) | ((unsigned int)f2bf(acc[nt][1]) << 16);
            pk.y = f2bf(acc[nt][2]) | ((unsigned int)f2bf(acc[nt][3]) << 16);
            size_t didx = (((((size_t)dir * 32 + s_loc) * 16 + grp) * 8 + w_rec) * 8 + t_rec) * 64 + lane;
            gdst[didx] = pk;
          }
        }
      }
      __builtin_amdgcn_fence(__ATOMIC_RELEASE, "agent");
      __syncthreads();
      if (tid == 0)
        __hip_atomic_fetch_add(&gxd[c * 4 + btq], 1u, __ATOMIC_RELEASE, __HIP_MEMORY_SCOPE_AGENT);
    }
  }
}

// ---------------- K2: real-path score + CRF forward (prefetched) ----------------
__global__ void crf_kernel(const unsigned short* __restrict__ emit_f,
                           const unsigned short* __restrict__ emit_b,
                           const float* __restrict__ trans, const int* __restrict__ tags,
                           const int* __restrict__ lens, float* __restrict__ out) {
  const float LOG2E = 1.4426950408889634f, LN2 = 0.6931471805599453f;
  int b = blockIdx.x, lane = threadIdx.x;
  int len = lens[b];
  const int* tg = tags + b * 512;

  float rs = 0.f;
  for (int s = lane; s < len; s += 64) {
    int t1 = tg[s];
    size_t idx = ((size_t)b * 512 + s) * 32 + t1;
    float e = bf2f(emit_f[idx]) + bf2f(emit_b[idx]);
    if (s > 0) e += trans[tg[s - 1] * 32 + t1];
    rs += e;
  }
#pragma unroll
  for (int m = 32; m; m >>= 1) rs += __shfl_xor(rs, m);

  int j = lane & 31, half = lane >> 5, i0 = half * 16;
  float tr[16];
#pragma unroll
  for (int ii = 0; ii < 16; ii++) tr[ii] = trans[(i0 + ii) * 32 + j];
  size_t base = (size_t)b * 512 * 32 + j;
  float alpha = bf2f(emit_f[base]) + bf2f(emit_b[base]);
  float e1 = 0.f, e2 = 0.f;
  if (len > 1) e1 = bf2f(emit_f[base + 32]) + bf2f(emit_b[base + 32]);
  if (len > 2) e2 = bf2f(emit_f[base + 64]) + bf2f(emit_b[base + 64]);
  for (int s = 1; s < len; s++) {
    float e3 = 0.f;
    if (s + 2 < len) {
      size_t ix = base + (size_t)(s + 2) * 32;
      e3 = bf2f(emit_f[ix]) + bf2f(emit_b[ix]);
    }
    float v[16]; float m1 = -1e30f;
#pragma unroll
    for (int ii = 0; ii < 16; ii++) { v[ii] = __shfl(alpha, i0 + ii) + tr[ii]; m1 = fmaxf(m1, v[ii]); }
    float m2 = fmaxf(m1, __shfl_xor(m1, 32));
    float sum = 0.f;
#pragma unroll
    for (int ii = 0; ii < 16; ii++) sum += __builtin_amdgcn_exp2f((v[ii] - m2) * LOG2E);
    sum += __shfl_xor(sum, 32);
    alpha = m2 + LN2 * __builtin_amdgcn_logf(sum) + e1;   // amdgcn logf == log2
    e1 = e2; e2 = e3;
  }
  float mz = alpha;
#pragma unroll
  for (int m = 16; m; m >>= 1) mz = fmaxf(mz, __shfl_xor(mz, m));
  float sz = __builtin_amdgcn_exp2f((alpha - mz) * LOG2E);
#pragma unroll
  for (int m = 16; m; m >>= 1) sz += __shfl_xor(sz, m);
  float logz = mz + LN2 * __builtin_amdgcn_logf(sz);
  if (lane == 0) out[b] = logz - rs;
}

// ---------------- launch ----------------
extern "C" void kernel_launch(void* const* d_in, const int* in_sizes, int n_in,
                              void* d_out, int out_size, void* d_ws, size_t ws_size,
                              hipStream_t stream) {
  const float* emb   = (const float*)d_in[0];
  const float* Wih_f = (const float*)d_in[1];
  const float* Whh_f = (const float*)d_in[2];
  const float* bih_f = (const float*)d_in[3];
  const float* bhh_f = (const float*)d_in[4];
  const float* Wih_b = (const float*)d_in[5];
  const float* Whh_b = (const float*)d_in[6];
  const float* bih_b = (const float*)d_in[7];
  const float* bhh_b = (const float*)d_in[8];
  const float* Wout  = (const float*)d_in[9];
  const float* bout  = (const float*)d_in[10];
  const float* trans = (const float*)d_in[11];
  const int* sent = (const int*)d_in[12];
  const int* tags = (const int*)d_in[13];
  const int* lens = (const int*)d_in[14];
  float* out = (float*)d_out;

  // workspace layout (bytes), total 85,475,840
  char* ws = (char*)d_ws;
  if (ws_size < 85475840ull) return;
  uint2*          gx      = (uint2*)(ws);                         // 67,108,864 (2 packed slots)
  unsigned short* emit_f  = (unsigned short*)(ws + 67108864);     //  8,388,608
  unsigned short* emit_b  = (unsigned short*)(ws + 75497472);     //  8,388,608
  unsigned short* wih_bf  = (unsigned short*)(ws + 83886080);     //  1,048,576
  unsigned char*  whh8    = (unsigned char*)(ws + 84934656);      //    524,288
  unsigned char*  wout8   = (unsigned char*)(ws + 85458944);      //     16,384
  unsigned int*   flg     = (unsigned int*)(ws + 85475328);       //        512

  cvt_weights<<<1040, 256, 0, stream>>>(Wih_f, Wih_b, Whh_f, Whh_b, Wout,
                                        wih_bf, whh8, wout8, flg);
  fused<<<256, 512, 0, stream>>>(emb, sent, lens, wih_bf, whh8, wout8,
                                 bih_f, bhh_f, bih_b, bhh_b, bout,
                                 gx, emit_f, emit_b, flg);
  crf_kernel<<<256, 64, 0, stream>>>(emit_f, emit_b, trans, tags, lens, out);
}